// Round 9
// baseline (11176.749 us; speedup 1.0000x reference)
//
#include <hip/hip_runtime.h>
#include <hip/hip_bf16.h>
#include <cstddef>

#define THRESH 1e-6f

__device__ __forceinline__ float thrf(float x) { return x > THRESH ? x : 0.0f; }
__device__ __forceinline__ float sigm(float x) { return 1.0f / (1.0f + expf(-x)); }
__device__ __forceinline__ float dot4(float4 a, float4 b) {
    return a.x * b.x + a.y * b.y + a.z * b.z + a.w * b.w;
}

// LDS index map for h: insert a 4-float pad every 64 floats so the 8 ks-chunk
// base addresses (k = ks*64) land on distinct bank groups.  Unpadded, ks*64
// mod 32 == 0 for all ks -> every lane octet hits the same 4 banks = 8-way
// conflict on ds_read_b128 (~2.9x, m136).  Padded: base bank = ks*4 -> spread.
#define HIDX(k) ((k) + (((k) >> 6) << 2))

// ---------------------------------------------------------------------------
// K1: tiled fp32 GEMM, BM=32 BN=64 BK=32, 256 threads, 2x4 micro-tile.
// GATHER: A row r = thr(W1[tok[bm+r]][k] + b1[k])   (embed path)
// BT:     B is (N,K) row-major, use B^T             (xproj path)
// ---------------------------------------------------------------------------
template <bool BT, bool GATHER, bool DO_THR>
__global__ __launch_bounds__(256) void k_gemm(const float* __restrict__ A,
                                              const float* __restrict__ Bm,
                                              const float* __restrict__ bias,
                                              float* __restrict__ C,
                                              const int* __restrict__ tok,
                                              const float* __restrict__ b1,
                                              const float* __restrict__ W1,
                                              int M, int N, int K) {
    constexpr int BM = 32, BN = 64, BK = 32;
    __shared__ float As[BK][BM + 1];
    __shared__ float Bs[BK][BN];

    const int tid = threadIdx.x;
    const int bm = blockIdx.x * BM;
    const int bn = blockIdx.y * BN;
    const int tn = (tid & 15) * 4;
    const int tm = (tid >> 4) * 2;

    float acc[2][4] = {};

    for (int k0 = 0; k0 < K; k0 += BK) {
        {
            int c4 = (tid & 7) * 4;
            int r  = tid >> 3;       // 0..31
            float4 v;
            if (GATHER) {
                int tv = tok[bm + r];
                float4 w  = *(const float4*)(W1 + (size_t)tv * K + k0 + c4);
                float4 bb = *(const float4*)(b1 + k0 + c4);
                v.x = thrf(w.x + bb.x); v.y = thrf(w.y + bb.y);
                v.z = thrf(w.z + bb.z); v.w = thrf(w.w + bb.w);
            } else {
                v = *(const float4*)(A + (size_t)(bm + r) * K + k0 + c4);
            }
            As[c4 + 0][r] = v.x;
            As[c4 + 1][r] = v.y;
            As[c4 + 2][r] = v.z;
            As[c4 + 3][r] = v.w;
        }
        if (!BT) {
            for (int i = tid; i < BK * BN / 4; i += 256) {
                int n4 = (i & 15) * 4;
                int kk = i >> 4;
                *(float4*)&Bs[kk][n4] = *(const float4*)(Bm + (size_t)(k0 + kk) * N + bn + n4);
            }
        } else {
            for (int i = tid; i < BN * BK / 4; i += 256) {
                int c4 = (i & 7) * 4;
                int n  = i >> 3;     // 0..63
                float4 v = *(const float4*)(Bm + (size_t)(bn + n) * K + k0 + c4);
                Bs[c4 + 0][n] = v.x;
                Bs[c4 + 1][n] = v.y;
                Bs[c4 + 2][n] = v.z;
                Bs[c4 + 3][n] = v.w;
            }
        }
        __syncthreads();

        for (int k = 0; k < BK; ++k) {
            float a0 = As[k][tm + 0], a1 = As[k][tm + 1];
            float b0 = Bs[k][tn + 0], b1v = Bs[k][tn + 1];
            float b2v = Bs[k][tn + 2], b3v = Bs[k][tn + 3];
            acc[0][0] += a0 * b0;  acc[0][1] += a0 * b1v;
            acc[0][2] += a0 * b2v; acc[0][3] += a0 * b3v;
            acc[1][0] += a1 * b0;  acc[1][1] += a1 * b1v;
            acc[1][2] += a1 * b2v; acc[1][3] += a1 * b3v;
        }
        __syncthreads();
    }

    const float4 bv = *(const float4*)(bias + bn + tn);
    for (int i = 0; i < 2; ++i) {
        int m = bm + tm + i;
        float4 o;
        o.x = acc[i][0] + bv.x;
        o.y = acc[i][1] + bv.y;
        o.z = acc[i][2] + bv.z;
        o.w = acc[i][3] + bv.w;
        if (DO_THR) { o.x = thrf(o.x); o.y = thrf(o.y); o.z = thrf(o.z); o.w = thrf(o.w); }
        *(float4*)(C + (size_t)m * N + bn + tn) = o;
    }
}

// ---------------------------------------------------------------------------
// K2: barrier-free GRU scan.  32 blocks (one per BATCH ROW) x 1024 threads.
// h[b] lives in LDS (double-buffered) for the whole scan -> zero inter-block
// communication, zero fences, zero global h traffic.  W_hh (3 MB) streams
// from XCD L2 every step (resident: 3 MB < 4 MB, ~4 blocks/XCD share it).
//
// Thread tid: jg = tid>>3 (owns j = jg*4+jj, jj<4), ks = tid&7 (k-chunk 64).
// Per step: 12 dots (4 j x 3 gates) over 64 k -> butterfly shfl_xor over ks
// -> ks==0 lanes finalize 4 j's -> write h' to other LDS buffer -> barrier.
// ---------------------------------------------------------------------------
__global__ __launch_bounds__(1024, 4) void k_gru_scan(const float* __restrict__ xp,    // (128,32,1536), b_ih included
                                                      const float* __restrict__ W_hh,  // (1536,512)
                                                      const float* __restrict__ b_hh,  // (1536)
                                                      float* __restrict__ h_out) {     // (32,512) final h
    __shared__ __align__(16) float hbuf[2][544];   // 512 + 8*4 pad (HIDX)

    const int tid = threadIdx.x;
    const int b   = blockIdx.x;      // batch row
    const int jg  = tid >> 3;        // 0..127
    const int ks  = tid & 7;         // 0..7
    const int kb  = ks * 64;

    // 12 loop-invariant W_hh row pointers + biases
    const float* wp[3][4];
    float bias[3][4];
#pragma unroll
    for (int g = 0; g < 3; ++g)
#pragma unroll
        for (int jj = 0; jj < 4; ++jj) {
            int row = g * 512 + jg * 4 + jj;
            wp[g][jj]   = W_hh + (size_t)row * 512 + kb;
            bias[g][jj] = b_hh[row];
        }

    if (tid < 544) { hbuf[0][tid] = 0.f; hbuf[1][tid] = 0.f; }
    __syncthreads();

    const float* xpb = xp + (size_t)b * 1536;

    for (int t = 0; t < 128; ++t) {
        const float* hc   = hbuf[t & 1];
        float*       hnew = hbuf[(t & 1) ^ 1];

        // xp loads issued early; in flight under the 768-FMA dot loop
        float xg[3][4];
        if (ks == 0) {
            const float* xpt = xpb + (size_t)t * 32 * 1536;
#pragma unroll
            for (int g = 0; g < 3; ++g)
#pragma unroll
                for (int jj = 0; jj < 4; ++jj)
                    xg[g][jj] = xpt[g * 512 + jg * 4 + jj];
        }

        float acc[3][4] = {};
        const float* hcb = &hc[HIDX(kb)];   // chunk is contiguous inside pad boundary
#pragma unroll 2
        for (int i = 0; i < 16; ++i) {
            float4 hv = *(const float4*)(hcb + i * 4);
#pragma unroll
            for (int g = 0; g < 3; ++g)
#pragma unroll
                for (int jj = 0; jj < 4; ++jj)
                    acc[g][jj] += dot4(hv, *(const float4*)(wp[g][jj] + i * 4));
        }

        // butterfly reduce over ks (lanes xor 1,2,4 within the wave)
#pragma unroll
        for (int m = 1; m < 8; m <<= 1)
#pragma unroll
            for (int g = 0; g < 3; ++g)
#pragma unroll
                for (int jj = 0; jj < 4; ++jj)
                    acc[g][jj] += __shfl_xor(acc[g][jj], m);

        if (ks == 0) {
#pragma unroll
            for (int jj = 0; jj < 4; ++jj) {
                int j = jg * 4 + jj;
                float r = sigm(xg[0][jj] + acc[0][jj] + bias[0][jj]);
                float z = sigm(xg[1][jj] + acc[1][jj] + bias[1][jj]);
                float n = tanhf(xg[2][jj] + r * (acc[2][jj] + bias[2][jj]));
                hnew[HIDX(j)] = (1.f - z) * n + z * hc[HIDX(j)];
            }
        }
        __syncthreads();   // all reads of hc done + hnew visible before next step
    }

    // t=127 wrote hbuf[0]
    if (tid < 512) h_out[(size_t)b * 512 + tid] = hbuf[0][HIDX(tid)];
}

// ---------------------------------------------------------------------------
// K3: head.  out[b][o] = sum_k h[b][k] * W3[k][o] + b3[o]
// ---------------------------------------------------------------------------
__global__ __launch_bounds__(256) void k_head(const float* __restrict__ h,
                                              const float* __restrict__ W3,
                                              const float* __restrict__ b3,
                                              float* __restrict__ out) {
    const int b = blockIdx.x;
    const int o = threadIdx.x;
    const float* hrow = h + (size_t)b * 512;
    float acc = b3[o];
#pragma unroll 8
    for (int k = 0; k < 512; ++k)
        acc += hrow[k] * W3[(size_t)k * 256 + o];
    out[(size_t)b * 256 + o] = acc;
}

// ---------------------------------------------------------------------------
extern "C" void kernel_launch(void* const* d_in, const int* in_sizes, int n_in,
                              void* d_out, int out_size, void* d_ws, size_t ws_size,
                              hipStream_t stream) {
    // setup_inputs() dict order:
    //   0:input 1:W1 2:b1 3:W2 4:b2 5:W_ih 6:W_hh 7:b_ih 8:b_hh 9:W3 10:b3
    const int*   tok  = (const int*)d_in[0];
    const float* W1   = (const float*)d_in[1];
    const float* b1   = (const float*)d_in[2];
    const float* W2   = (const float*)d_in[3];
    const float* b2   = (const float*)d_in[4];
    const float* W_ih = (const float*)d_in[5];
    const float* W_hh = (const float*)d_in[6];
    const float* b_ih = (const float*)d_in[7];
    const float* b_hh = (const float*)d_in[8];
    const float* W3   = (const float*)d_in[9];
    const float* b3   = (const float*)d_in[10];
    float* out = (float*)d_out;

    // workspace (floats): emb 4MB | xp 24MB | h_a 64KB  (~28.1 MB)
    float* ws  = (float*)d_ws;
    float* emb = ws;                 // 4096*256
    float* xp  = ws + 1048576;       // 4096*1536
    float* h_a = xp + 6291456;       // 32*512
    // no memset needed: emb/xp/h_a are all fully written before being read

    // K1a: emb = thr(thr(W1[tok]+b1) @ W2 + b2)      (gather fused into A)
    k_gemm<false, true, true><<<dim3(4096 / 32, 256 / 64), 256, 0, stream>>>(
        nullptr, W2, b2, emb, tok, b1, W1, 4096, 256, 512);

    // K1b: xp = emb @ W_ih^T + b_ih                  (4096 x 1536)
    k_gemm<true, false, false><<<dim3(4096 / 32, 1536 / 64), 256, 0, stream>>>(
        emb, W_ih, b_ih, xp, nullptr, nullptr, nullptr, 4096, 1536, 256);

    // K2: barrier-free scan, one batch row per block, h resident in LDS
    k_gru_scan<<<32, 1024, 0, stream>>>(xp, W_hh, b_hh, h_a);

    // K3: head on final hidden state
    k_head<<<32, 256, 0, stream>>>(h_a, W3, b3, out);
}